// Round 5
// baseline (803.262 us; speedup 1.0000x reference)
//
#include <hip/hip_runtime.h>

// Problem constants
#define WW 256
#define NB 128      // batch N
#define CD 512      // channels
#define NE 8        // heads
#define HD 64       // head dim
#define NCHUNKS 4
#define SCALING 0.125f

typedef __attribute__((ext_vector_type(8))) short bfx8;
typedef __attribute__((ext_vector_type(4))) float fx4;
typedef __attribute__((ext_vector_type(2))) float fx2;

// workspace layout (float offsets)
#define OFF_WPB    131072u          // 1536*512 bf16
#define OFF_OWB    524288u          // 512*512 bf16
#define OFF_S      655360u
#define OFF_U      656896u
#define OFF_PQ     658432u          // 511*512 bf16 (scaled q_r)
#define OFF_PK     789504u          // 511*512 bf16
#define OFF_QB     920576u          // 256*128*512 bf16
#define OFF_KB     9309184u
#define OFF_VB     17697792u
#define OFF_ATTN   26086400u        // attnb bf16 (33.5MB) + vob4 bf16 (33.5MB)
#define OFF_T3     42863616u        // 8*256*128*64 bf16 (posb/ipwb overlay pre-loop)
#define OFF_PB     51252224u        // 128*8*64*256 bf16 probs
// total ~61.7M floats = 247 MB

// ---------------------------------------------------------------------------
__device__ __forceinline__ unsigned short f2bf(float f) {
  unsigned u = __builtin_bit_cast(unsigned, f);
  u = (u + 0x7fffu + ((u >> 16) & 1u)) >> 16;
  return (unsigned short)u;
}
__device__ __forceinline__ float bf2f(unsigned short h) {
  unsigned u = ((unsigned)h) << 16;
  return __builtin_bit_cast(float, u);
}
__device__ __forceinline__ int packbf(float lo, float hi) {
  return (int)(((unsigned)f2bf(hi) << 16) | f2bf(lo));
}
// HW packed convert: lo -> low 16, hi -> high 16 (RNE, same as f2bf)
__device__ __forceinline__ int cvtpk(float lo, float hi) {
  int r;
  asm("v_cvt_pk_bf16_f32 %0, %1, %2" : "=v"(r) : "v"(lo), "v"(hi));
  return r;
}

#define GLDS16(g, l)                                                          \
  __builtin_amdgcn_global_load_lds(                                           \
      (const __attribute__((address_space(1))) void*)(g),                     \
      (__attribute__((address_space(3))) void*)(l), 16, 0, 0)

// ---------------------------------------------------------------------------
// fp32 -> bf16 convert
__global__ __launch_bounds__(256) void cvt_kernel(const float* __restrict__ a,
                                                  unsigned short* __restrict__ b,
                                                  int n8) {
  int i = blockIdx.x * 256 + threadIdx.x;
  if (i >= n8) return;
  float4 x = ((const float4*)a)[2 * i];
  float4 y = ((const float4*)a)[2 * i + 1];
  int4 o;
  o.x = packbf(x.x, x.y);
  o.y = packbf(x.z, x.w);
  o.z = packbf(y.x, y.y);
  o.w = packbf(y.z, y.w);
  ((int4*)b)[i] = o;
}

// ---------------------------------------------------------------------------
// Fold ln_w into in_proj_w (bf16); per-output-row constants S,U.
__global__ __launch_bounds__(256) void prep_kernel(const float* __restrict__ ipw,
                                                   const float* __restrict__ ipb,
                                                   const float* __restrict__ lnw,
                                                   const float* __restrict__ lnb,
                                                   unsigned short* __restrict__ Wpb,
                                                   float* __restrict__ S,
                                                   float* __restrict__ U) {
  int o = blockIdx.x, t = threadIdx.x;
  float s = 0.f, u = 0.f;
#pragma unroll
  for (int j0 = 0; j0 < 512; j0 += 256) {
    int j = j0 + t;
    float w0 = ipw[(size_t)o * 512 + j];
    float wl = w0 * lnw[j];
    unsigned short h = f2bf(wl);
    Wpb[(size_t)o * 512 + j] = h;
    s += bf2f(h);
    u += w0 * lnb[j];
  }
  __shared__ float rs[4], ru[4];
  int lane = t & 63, wv = t >> 6;
#pragma unroll
  for (int off = 32; off > 0; off >>= 1) { s += __shfl_xor(s, off); u += __shfl_xor(u, off); }
  if (lane == 0) { rs[wv] = s; ru[wv] = u; }
  __syncthreads();
  if (t == 0) {
    S[o] = rs[0] + rs[1] + rs[2] + rs[3];
    U[o] = ru[0] + ru[1] + ru[2] + ru[3] + ipb[o];
  }
}

// ---------------------------------------------------------------------------
// bf16 MFMA GEMM over fp32 A with fused in-block LN stats + fold epilogue.
// A reg-staged (HW cvt_pk + packed-f32 stats during staging, ds_write to
// swizzled slot); B via global_load_lds. dbuf + counted vmcnt.
// grid: x = n-tiles (fast: blocks sharing an A-tile run together), y = m-tiles
__global__ __launch_bounds__(256) void gemm_ln(const float* __restrict__ A,
                                               const unsigned short* __restrict__ Bw,
                                               const float* __restrict__ S,
                                               const float* __restrict__ U,
                                               unsigned short* __restrict__ out0,
                                               unsigned short* __restrict__ out1,
                                               int wOff, float scale) {
  __shared__ unsigned short As[2][128 * 32];
  __shared__ unsigned short Bs[2][128 * 32];
  __shared__ float sm[128], sv[128];
  int t = threadIdx.x;
  int lane = t & 63, w = t >> 6;
  int quad = lane >> 4, l15 = lane & 15;
  int wm = w >> 1, wn = w & 1;
  int n0 = blockIdx.x * 128, m0 = blockIdx.y * 128;

  int swz = (lane & 3) ^ ((lane >> 3) & 3);        // involution slot swizzle
  int row0 = w * 16 + (lane >> 2);                 // local A row (first half)
  unsigned aw0 = (unsigned)row0 * 32 + swz * 8;    // ds_write offset (ushorts)
  unsigned aw1 = aw0 + 64 * 32;
  unsigned lo0 = (unsigned)(w * 16) * 32;          // B GLDS dests
  unsigned lo1 = (unsigned)(64 + w * 16) * 32;

  const float* gA0 = A + (size_t)(m0 + row0) * 512 + (lane & 3) * 8;
  const float* gA1 = gA0 + (size_t)64 * 512;
  int cs = swz * 8;                                // B source pre-swizzle
  const unsigned short* gB0 = Bw + (size_t)(wOff + n0 + w * 16 + (lane >> 2)) * 512 + cs;
  const unsigned short* gB1 = gB0 + (size_t)64 * 512;

  fx4 acc[4][4];
#pragma unroll
  for (int i = 0; i < 4; ++i)
#pragma unroll
    for (int j = 0; j < 4; ++j) acc[i][j] = (fx4){0.f, 0.f, 0.f, 0.f};

  int ro = (quad ^ ((l15 >> 1) & 3)) * 8;          // read-side swizzle

  float4 a00, a01, a10, a11;
  fx2 s20 = (fx2){0.f, 0.f}, ss20 = (fx2){0.f, 0.f};
  fx2 s21 = (fx2){0.f, 0.f}, ss21 = (fx2){0.f, 0.f};

#define LOADA(kk)                                                             \
  do {                                                                        \
    a00 = *(const float4*)(gA0 + (kk));                                       \
    a01 = *(const float4*)(gA0 + (kk) + 4);                                   \
    a10 = *(const float4*)(gA1 + (kk));                                       \
    a11 = *(const float4*)(gA1 + (kk) + 4);                                   \
  } while (0)

#define CVTSTATS(buf)                                                         \
  do {                                                                        \
    int4 w0v, w1v;                                                            \
    w0v.x = cvtpk(a00.x, a00.y); w0v.y = cvtpk(a00.z, a00.w);                 \
    w0v.z = cvtpk(a01.x, a01.y); w0v.w = cvtpk(a01.z, a01.w);                 \
    w1v.x = cvtpk(a10.x, a10.y); w1v.y = cvtpk(a10.z, a10.w);                 \
    w1v.z = cvtpk(a11.x, a11.y); w1v.w = cvtpk(a11.z, a11.w);                 \
    *(int4*)(&As[buf][aw0]) = w0v;                                            \
    *(int4*)(&As[buf][aw1]) = w1v;                                            \
    fx2 p;                                                                    \
    p = (fx2){a00.x, a00.y}; s20 += p; ss20 += p * p;                         \
    p = (fx2){a00.z, a00.w}; s20 += p; ss20 += p * p;                         \
    p = (fx2){a01.x, a01.y}; s20 += p; ss20 += p * p;                         \
    p = (fx2){a01.z, a01.w}; s20 += p; ss20 += p * p;                         \
    p = (fx2){a10.x, a10.y}; s21 += p; ss21 += p * p;                         \
    p = (fx2){a10.z, a10.w}; s21 += p; ss21 += p * p;                         \
    p = (fx2){a11.x, a11.y}; s21 += p; ss21 += p * p;                         \
    p = (fx2){a11.z, a11.w}; s21 += p; ss21 += p * p;                         \
  } while (0)

#define GLDSB(buf, kk)                                                        \
  do {                                                                        \
    GLDS16(gB0 + (kk), &Bs[buf][lo0]);                                        \
    GLDS16(gB1 + (kk), &Bs[buf][lo1]);                                        \
  } while (0)

#define COMPUTE_G(buf)                                                        \
  do {                                                                        \
    const unsigned short* Ab = &As[buf][0];                                   \
    const unsigned short* Bb = &Bs[buf][0];                                   \
    bfx8 af[4], bfr[4];                                                       \
    _Pragma("unroll")                                                         \
    for (int i = 0; i < 4; ++i)                                               \
      af[i] = *(const bfx8*)(Ab + (size_t)(wm * 64 + i * 16 + l15) * 32 + ro);\
    _Pragma("unroll")                                                         \
    for (int j = 0; j < 4; ++j)                                               \
      bfr[j] = *(const bfx8*)(Bb + (size_t)(wn * 64 + j * 16 + l15) * 32 + ro);\
    _Pragma("unroll")                                                         \
    for (int i = 0; i < 4; ++i)                                               \
      _Pragma("unroll")                                                       \
      for (int j = 0; j < 4; ++j)                                             \
        acc[i][j] = __builtin_amdgcn_mfma_f32_16x16x32_bf16(af[i], bfr[j], acc[i][j], 0, 0, 0); \
  } while (0)

  LOADA(0);
  __builtin_amdgcn_sched_barrier(0);
  GLDSB(0, 0);
  __builtin_amdgcn_sched_barrier(0);
  int cur = 0;
  for (int kt = 0; kt < 480; kt += 32) {
    asm volatile("s_waitcnt vmcnt(2)" ::: "memory");   // A regs ready
    CVTSTATS(cur);
    __builtin_amdgcn_sched_barrier(0);
    LOADA(kt + 32);
    __builtin_amdgcn_sched_barrier(0);
    GLDSB(cur ^ 1, kt + 32);
    __builtin_amdgcn_sched_barrier(0);
    asm volatile("s_waitcnt vmcnt(6) lgkmcnt(0)" ::: "memory");  // B(cur)+ds_writes done
    __builtin_amdgcn_s_barrier();
    __builtin_amdgcn_sched_barrier(0);
    COMPUTE_G(cur);
    __builtin_amdgcn_s_barrier();
    __builtin_amdgcn_sched_barrier(0);
    cur ^= 1;
  }
  asm volatile("s_waitcnt vmcnt(2)" ::: "memory");
  CVTSTATS(cur);
  __builtin_amdgcn_sched_barrier(0);
  asm volatile("s_waitcnt vmcnt(0) lgkmcnt(0)" ::: "memory");
  __builtin_amdgcn_s_barrier();
  __builtin_amdgcn_sched_barrier(0);
  COMPUTE_G(cur);

  // finalize stats: combine packed halves, reduce across 4 lanes per row
  float s0 = s20.x + s20.y, ss0 = ss20.x + ss20.y;
  float s1 = s21.x + s21.y, ss1 = ss21.x + ss21.y;
  s0 += __shfl_xor(s0, 1); s0 += __shfl_xor(s0, 2);
  ss0 += __shfl_xor(ss0, 1); ss0 += __shfl_xor(ss0, 2);
  s1 += __shfl_xor(s1, 1); s1 += __shfl_xor(s1, 2);
  ss1 += __shfl_xor(ss1, 1); ss1 += __shfl_xor(ss1, 2);
  if ((lane & 3) == 0) {
    float m0v = s0 * (1.0f / 512.0f);
    float v0v = ss0 * (1.0f / 512.0f) - m0v * m0v;
    sm[row0] = m0v; sv[row0] = rsqrtf(v0v + 1e-5f);
    float m1v = s1 * (1.0f / 512.0f);
    float v1v = ss1 * (1.0f / 512.0f) - m1v * m1v;
    sm[row0 + 64] = m1v; sv[row0 + 64] = rsqrtf(v1v + 1e-5f);
  }
  __syncthreads();

  float mn[16], rs[16];
#pragma unroll
  for (int i = 0; i < 4; ++i)
#pragma unroll
    for (int r = 0; r < 4; ++r) {
      int ml = wm * 64 + i * 16 + quad * 4 + r;
      mn[i * 4 + r] = sm[ml];
      rs[i * 4 + r] = sv[ml];
    }
#pragma unroll
  for (int j = 0; j < 4; ++j) {
    int oc = n0 + wn * 64 + j * 16 + l15;
    int o = wOff + oc;
    float Sv = S[o], Uv = U[o];
    unsigned short* dst; int cc;
    if (oc < 512) { dst = out0; cc = oc; } else { dst = out1; cc = oc - 512; }
#pragma unroll
    for (int i = 0; i < 4; ++i)
#pragma unroll
      for (int r = 0; r < 4; ++r) {
        int m = m0 + wm * 64 + i * 16 + quad * 4 + r;
        dst[(size_t)m * 512 + cc] =
            f2bf(((acc[i][j][r] - mn[i * 4 + r] * Sv) * rs[i * 4 + r] + Uv) * scale);
      }
  }
#undef LOADA
#undef CVTSTATS
#undef GLDSB
#undef COMPUTE_G
}

// ---------------------------------------------------------------------------
// bf16 MFMA GEMM out-proj over ALL chunks: out[g,o] = fl[g,o] + vob4@owb + ob
__global__ __launch_bounds__(256) void gemm_out(const unsigned short* __restrict__ A,
                                                const unsigned short* __restrict__ Bw,
                                                const float* __restrict__ ob,
                                                const float* __restrict__ fl,
                                                float* __restrict__ out) {
  __shared__ unsigned short As[2][128 * 32];
  __shared__ unsigned short Bs[2][128 * 32];
  int t = threadIdx.x;
  int lane = t & 63, w = t >> 6;
  int quad = lane >> 4, l15 = lane & 15;
  int wm = w >> 1, wn = w & 1;
  int n0 = blockIdx.x * 128, m0 = blockIdx.y * 128;

  int cs = ((lane & 3) ^ ((lane >> 3) & 3)) * 8;
  unsigned lo0 = (unsigned)(w * 16) * 32;
  unsigned lo1 = (unsigned)(64 + w * 16) * 32;
  const unsigned short* gA0 = A + (size_t)(m0 + w * 16 + (lane >> 2)) * 512 + cs;
  const unsigned short* gA1 = gA0 + (size_t)64 * 512;
  const unsigned short* gB0 = Bw + (size_t)(n0 + w * 16 + (lane >> 2)) * 512 + cs;
  const unsigned short* gB1 = gB0 + (size_t)64 * 512;

  fx4 acc[4][4];
#pragma unroll
  for (int i = 0; i < 4; ++i)
#pragma unroll
    for (int j = 0; j < 4; ++j) acc[i][j] = (fx4){0.f, 0.f, 0.f, 0.f};

  int ro = (quad ^ ((l15 >> 1) & 3)) * 8;

#define STAGE_O(buf, kk)                                                      \
  do {                                                                        \
    GLDS16(gA0 + (kk), &As[buf][lo0]);                                        \
    GLDS16(gA1 + (kk), &As[buf][lo1]);                                        \
    GLDS16(gB0 + (kk), &Bs[buf][lo0]);                                        \
    GLDS16(gB1 + (kk), &Bs[buf][lo1]);                                        \
  } while (0)

#define COMPUTE_O(buf)                                                        \
  do {                                                                        \
    const unsigned short* Ab = &As[buf][0];                                   \
    const unsigned short* Bb = &Bs[buf][0];                                   \
    bfx8 af[4], bfr[4];                                                       \
    _Pragma("unroll")                                                         \
    for (int i = 0; i < 4; ++i)                                               \
      af[i] = *(const bfx8*)(Ab + (size_t)(wm * 64 + i * 16 + l15) * 32 + ro);\
    _Pragma("unroll")                                                         \
    for (int j = 0; j < 4; ++j)                                               \
      bfr[j] = *(const bfx8*)(Bb + (size_t)(wn * 64 + j * 16 + l15) * 32 + ro);\
    _Pragma("unroll")                                                         \
    for (int i = 0; i < 4; ++i)                                               \
      _Pragma("unroll")                                                       \
      for (int j = 0; j < 4; ++j)                                             \
        acc[i][j] = __builtin_amdgcn_mfma_f32_16x16x32_bf16(af[i], bfr[j], acc[i][j], 0, 0, 0); \
  } while (0)

  STAGE_O(0, 0);
  int cur = 0;
  for (int kt = 0; kt < 480; kt += 32) {
    STAGE_O(cur ^ 1, kt + 32);
    asm volatile("s_waitcnt vmcnt(4)" ::: "memory");
    __builtin_amdgcn_s_barrier();
    __builtin_amdgcn_sched_barrier(0);
    COMPUTE_O(cur);
    asm volatile("s_waitcnt lgkmcnt(0)" ::: "memory");
    __builtin_amdgcn_s_barrier();
    __builtin_amdgcn_sched_barrier(0);
    cur ^= 1;
  }
  asm volatile("s_waitcnt vmcnt(0)" ::: "memory");
  __builtin_amdgcn_s_barrier();
  __builtin_amdgcn_sched_barrier(0);
  COMPUTE_O(cur);

#pragma unroll
  for (int j = 0; j < 4; ++j) {
    int o = n0 + wn * 64 + j * 16 + l15;
    float bias = ob[o];
#pragma unroll
    for (int i = 0; i < 4; ++i)
#pragma unroll
      for (int r = 0; r < 4; ++r) {
        int m = m0 + wm * 64 + i * 16 + quad * 4 + r;
        size_t go = (size_t)m * 512 + o;
        out[go] = acc[i][j][r] + bias + fl[go];
      }
  }
#undef STAGE_O
#undef COMPUTE_O
}

// ---------------------------------------------------------------------------
// pos table projection via MFMA (bf16 inputs converted by cvt_kernel).
__global__ __launch_bounds__(256) void posproj_mfma(const unsigned short* __restrict__ Apos,
                                                    const unsigned short* __restrict__ Bw,
                                                    const float* __restrict__ ipb,
                                                    unsigned short* __restrict__ Pq,
                                                    unsigned short* __restrict__ Pk) {
  __shared__ unsigned short As[2][128 * 32];
  __shared__ unsigned short Bs[2][128 * 32];
  int t = threadIdx.x;
  int lane = t & 63, w = t >> 6;
  int quad = lane >> 4, l15 = lane & 15;
  int wm = w >> 1, wn = w & 1;
  int m0 = blockIdx.x * 128, n0 = blockIdx.y * 128;

  int cs = ((lane & 3) ^ ((lane >> 3) & 3)) * 8;
  unsigned lo0 = (unsigned)(w * 16) * 32;
  unsigned lo1 = (unsigned)(64 + w * 16) * 32;
  int ar0 = m0 + w * 16 + (lane >> 2); if (ar0 > 510) ar0 = 510;
  int ar1 = m0 + 64 + w * 16 + (lane >> 2); if (ar1 > 510) ar1 = 510;
  const unsigned short* gA0 = Apos + (size_t)ar0 * 512 + cs;
  const unsigned short* gA1 = Apos + (size_t)ar1 * 512 + cs;
  const unsigned short* gB0 = Bw + (size_t)(n0 + w * 16 + (lane >> 2)) * 512 + cs;
  const unsigned short* gB1 = gB0 + (size_t)64 * 512;

  fx4 acc[4][4];
#pragma unroll
  for (int i = 0; i < 4; ++i)
#pragma unroll
    for (int j = 0; j < 4; ++j) acc[i][j] = (fx4){0.f, 0.f, 0.f, 0.f};

  int ro = (quad ^ ((l15 >> 1) & 3)) * 8;

#define STAGE_P(buf, kk)                                                      \
  do {                                                                        \
    GLDS16(gA0 + (kk), &As[buf][lo0]);                                        \
    GLDS16(gA1 + (kk), &As[buf][lo1]);                                        \
    GLDS16(gB0 + (kk), &Bs[buf][lo0]);                                        \
    GLDS16(gB1 + (kk), &Bs[buf][lo1]);                                        \
  } while (0)

#define COMPUTE_P(buf)                                                        \
  do {                                                                        \
    const unsigned short* Ab = &As[buf][0];                                   \
    const unsigned short* Bb = &Bs[buf][0];                                   \
    bfx8 af[4], bfr[4];                                                       \
    _Pragma("unroll")                                                         \
    for (int i = 0; i < 4; ++i)                                               \
      af[i] = *(const bfx8*)(Ab + (size_t)(wm * 64 + i * 16 + l15) * 32 + ro);\
    _Pragma("unroll")                                                         \
    for (int j = 0; j < 4; ++j)                                               \
      bfr[j] = *(const bfx8*)(Bb + (size_t)(wn * 64 + j * 16 + l15) * 32 + ro);\
    _Pragma("unroll")                                                         \
    for (int i = 0; i < 4; ++i)                                               \
      _Pragma("unroll")                                                       \
      for (int j = 0; j < 4; ++j)                                             \
        acc[i][j] = __builtin_amdgcn_mfma_f32_16x16x32_bf16(af[i], bfr[j], acc[i][j], 0, 0, 0); \
  } while (0)

  STAGE_P(0, 0);
  int cur = 0;
  for (int kt = 0; kt < 480; kt += 32) {
    STAGE_P(cur ^ 1, kt + 32);
    asm volatile("s_waitcnt vmcnt(4)" ::: "memory");
    __builtin_amdgcn_s_barrier();
    __builtin_amdgcn_sched_barrier(0);
    COMPUTE_P(cur);
    asm volatile("s_waitcnt lgkmcnt(0)" ::: "memory");
    __builtin_amdgcn_s_barrier();
    __builtin_amdgcn_sched_barrier(0);
    cur ^= 1;
  }
  asm volatile("s_waitcnt vmcnt(0)" ::: "memory");
  __builtin_amdgcn_s_barrier();
  __builtin_amdgcn_sched_barrier(0);
  COMPUTE_P(cur);

#pragma unroll
  for (int j = 0; j < 4; ++j) {
    int o = n0 + wn * 64 + j * 16 + l15;
    float bias = ipb[o];
    float scale = (o < 512) ? SCALING : 1.0f;
    unsigned short* dst; int cc;
    if (o < 512) { dst = Pq; cc = o; } else { dst = Pk; cc = o - 512; }
#pragma unroll
    for (int i = 0; i < 4; ++i)
#pragma unroll
      for (int r = 0; r < 4; ++r) {
        int m = m0 + wm * 64 + i * 16 + quad * 4 + r;
        if (m < 511)
          dst[(size_t)m * 512 + cc] = f2bf((acc[i][j][r] + bias) * scale);
      }
  }
#undef STAGE_P
#undef COMPUTE_P
}

// ---------------------------------------------------------------------------
// term3 (bf16 MFMA): T3[e][v][n][wq] = sum_h k[v,n,e,h] * q_r[wq,v,e,h]
__global__ __launch_bounds__(256) void t3_kernel(const unsigned short* __restrict__ kb,
                                                 const unsigned short* __restrict__ Pq,
                                                 const int* __restrict__ idx,
                                                 unsigned short* __restrict__ T3, int wc) {
  __shared__ unsigned short As[128 * 72];
  __shared__ unsigned short Bs[64 * 72];
  int t = threadIdx.x, lane = t & 63, w = t >> 6;
  int quad = lane >> 4, l15 = lane & 15;
  int e = blockIdx.x, v = blockIdx.y;
  const unsigned short* asrc = kb + ((size_t)v * NB) * 512 + e * 64;
  for (int c = t; c < 1024; c += 256) {
    int row = c >> 3, c8 = c & 7;
    *(int4*)(As + row * 72 + c8 * 8) = *(const int4*)(asrc + (size_t)row * 512 + c8 * 8);
  }
  for (int c = t; c < 512; c += 256) {
    int row = c >> 3, c8 = c & 7;
    int ri = idx[(wc * 64 + row) * WW + v];
    *(int4*)(Bs + row * 72 + c8 * 8) = *(const int4*)(Pq + (size_t)ri * 512 + e * 64 + c8 * 8);
  }
  __syncthreads();
  fx4 acc[2][4];
#pragma unroll
  for (int i = 0; i < 2; ++i)
#pragma unroll
    for (int j = 0; j < 4; ++j) acc[i][j] = (fx4){0.f, 0.f, 0.f, 0.f};
#pragma unroll
  for (int kt = 0; kt < 64; kt += 32) {
    bfx8 af[2], bfr[4];
#pragma unroll
    for (int i = 0; i < 2; ++i)
      af[i] = *(const bfx8*)(As + (w * 32 + i * 16 + l15) * 72 + kt + quad * 8);
#pragma unroll
    for (int j = 0; j < 4; ++j)
      bfr[j] = *(const bfx8*)(Bs + (j * 16 + l15) * 72 + kt + quad * 8);
#pragma unroll
    for (int i = 0; i < 2; ++i)
#pragma unroll
      for (int j = 0; j < 4; ++j)
        acc[i][j] = __builtin_amdgcn_mfma_f32_16x16x32_bf16(af[i], bfr[j], acc[i][j], 0, 0, 0);
  }
#pragma unroll
  for (int i = 0; i < 2; ++i)
#pragma unroll
    for (int j = 0; j < 4; ++j)
#pragma unroll
      for (int r = 0; r < 4; ++r) {
        int n = w * 32 + i * 16 + quad * 4 + r;
        int wq = j * 16 + l15;
        T3[(((size_t)e * WW + v) * NB + n) * 64 + wq] = f2bf(acc[i][j][r]);
      }
}

// ---------------------------------------------------------------------------
// term1 + term3-merge (bf16 MFMA), write-only first writer of attnb (bf16)
__global__ __launch_bounds__(256) void t1_kernel(const unsigned short* __restrict__ qb,
                                                 const unsigned short* __restrict__ kb,
                                                 const unsigned short* __restrict__ T3,
                                                 unsigned short* __restrict__ attnb, int wc) {
  __shared__ unsigned short As[64 * 72];
  __shared__ unsigned short Bs[256 * 72];
  int t = threadIdx.x, lane = t & 63, w = t >> 6;
  int quad = lane >> 4, l15 = lane & 15;
  int e = blockIdx.x, n = blockIdx.y;
  const unsigned short* asrc = qb + ((size_t)(wc * 64) * NB + n) * 512 + e * 64;
  for (int c = t; c < 512; c += 256) {
    int row = c >> 3, c8 = c & 7;
    *(int4*)(As + row * 72 + c8 * 8) = *(const int4*)(asrc + (size_t)row * NB * 512 + c8 * 8);
  }
  const unsigned short* bsrc = kb + (size_t)n * 512 + e * 64;
  for (int c = t; c < 2048; c += 256) {
    int row = c >> 3, c8 = c & 7;
    *(int4*)(Bs + row * 72 + c8 * 8) = *(const int4*)(bsrc + (size_t)row * NB * 512 + c8 * 8);
  }
  __syncthreads();
  fx4 acc[4][4];
#pragma unroll
  for (int i = 0; i < 4; ++i)
#pragma unroll
    for (int j = 0; j < 4; ++j) acc[i][j] = (fx4){0.f, 0.f, 0.f, 0.f};
#pragma unroll
  for (int kt = 0; kt < 64; kt += 32) {
    bfx8 af[4], bfr[4];
#pragma unroll
    for (int i = 0; i < 4; ++i)
      af[i] = *(const bfx8*)(As + (i * 16 + l15) * 72 + kt + quad * 8);
#pragma unroll
    for (int j = 0; j < 4; ++j)
      bfr[j] = *(const bfx8*)(Bs + (w * 64 + j * 16 + l15) * 72 + kt + quad * 8);
#pragma unroll
    for (int i = 0; i < 4; ++i)
#pragma unroll
      for (int j = 0; j < 4; ++j)
        acc[i][j] = __builtin_amdgcn_mfma_f32_16x16x32_bf16(af[i], bfr[j], acc[i][j], 0, 0, 0);
  }
  __syncthreads();
  const unsigned short* tsrc = T3 + ((size_t)e * WW * NB + n) * 64;
  for (int c = t; c < 2048; c += 256) {
    int row = c >> 3, c8 = c & 7;
    *(int4*)(Bs + row * 72 + c8 * 8) = *(const int4*)(tsrc + (size_t)row * NB * 64 + c8 * 8);
  }
  __syncthreads();
#pragma unroll
  for (int i = 0; i < 4; ++i)
#pragma unroll
    for (int j = 0; j < 4; ++j) {
      int vg = w * 64 + j * 16 + l15;
      ushort4 t3v = *(const ushort4*)(Bs + (size_t)vg * 72 + i * 16 + quad * 4);
      const unsigned short tv[4] = {t3v.x, t3v.y, t3v.z, t3v.w};
#pragma unroll
      for (int r = 0; r < 4; ++r) {
        int wq = i * 16 + quad * 4 + r;
        attnb[(((size_t)n * NE + e) * 64 + wq) * WW + vg] = f2bf(acc[i][j][r] + bf2f(tv[r]));
      }
    }
}

// ---------------------------------------------------------------------------
// term2 + softmax fused; attn read is bf16
__global__ __launch_bounds__(256) void t2s_kernel(const unsigned short* __restrict__ qb,
                                                  const unsigned short* __restrict__ Pk,
                                                  const int* __restrict__ idx,
                                                  const unsigned short* __restrict__ attnb,
                                                  unsigned short* __restrict__ pbuf,
                                                  float* __restrict__ raw, int wc) {
  __shared__ unsigned short As[16 * 72];
  __shared__ unsigned short Bs[256 * 72];
  __shared__ int idxs[256];
  __shared__ float redm[16 * 4];
  __shared__ float reds[16 * 4];
  int t = threadIdx.x, lane = t & 63, w = t >> 6;
  int quad = lane >> 4, l15 = lane & 15;
  int wq = blockIdx.x, nt = blockIdx.y;
  int n0 = nt * 16;
  idxs[t] = idx[((size_t)(wc * 64 + wq)) * WW + t];

  fx4 raws[4];
#pragma unroll
  for (int j = 0; j < 4; ++j) raws[j] = (fx4){0.f, 0.f, 0.f, 0.f};

  const unsigned short* abase = qb + ((size_t)(wc * 64 + wq) * NB + n0) * 512;

  for (int e = 0; e < NE; ++e) {
    __syncthreads();
    if (t < 128) {
      int row = t >> 3, c8 = t & 7;
      *(int4*)(As + row * 72 + c8 * 8) = *(const int4*)(abase + (size_t)row * 512 + e * 64 + c8 * 8);
    }
    for (int c = t; c < 2048; c += 256) {
      int row = c >> 3, c8 = c & 7;
      int ri = idxs[row];
      *(int4*)(Bs + row * 72 + c8 * 8) = *(const int4*)(Pk + (size_t)ri * 512 + e * 64 + c8 * 8);
    }
    __syncthreads();

    fx4 acc[4];
#pragma unroll
    for (int j = 0; j < 4; ++j) acc[j] = (fx4){0.f, 0.f, 0.f, 0.f};
    bfx8 af0 = *(const bfx8*)(As + l15 * 72 + quad * 8);
    bfx8 af1 = *(const bfx8*)(As + l15 * 72 + 32 + quad * 8);
#pragma unroll
    for (int j = 0; j < 4; ++j) {
      bfx8 b0 = *(const bfx8*)(Bs + (w * 64 + j * 16 + l15) * 72 + quad * 8);
      acc[j] = __builtin_amdgcn_mfma_f32_16x16x32_bf16(af0, b0, acc[j], 0, 0, 0);
    }
#pragma unroll
    for (int j = 0; j < 4; ++j) {
      bfx8 b1 = *(const bfx8*)(Bs + (w * 64 + j * 16 + l15) * 72 + 32 + quad * 8);
      acc[j] = __builtin_amdgcn_mfma_f32_16x16x32_bf16(af1, b1, acc[j], 0, 0, 0);
    }

#pragma unroll
    for (int j = 0; j < 4; ++j) {
      int vg = w * 64 + j * 16 + l15;
#pragma unroll
      for (int r = 0; r < 4; ++r) {
        int n = n0 + quad * 4 + r;
        acc[j][r] += bf2f(attnb[(((size_t)n * NE + e) * 64 + wq) * WW + vg]);
      }
    }

    float rm[4];
#pragma unroll
    for (int r = 0; r < 4; ++r)
      rm[r] = fmaxf(fmaxf(acc[0][r], acc[1][r]), fmaxf(acc[2][r], acc[3][r]));
#pragma unroll
    for (int off = 1; off < 16; off <<= 1)
#pragma unroll
      for (int r = 0; r < 4; ++r) rm[r] = fmaxf(rm[r], __shfl_xor(rm[r], off));
    if (l15 == 0) {
#pragma unroll
      for (int r = 0; r < 4; ++r) redm[(quad * 4 + r) * 4 + w] = rm[r];
    }
    __syncthreads();
    float fm[4];
#pragma unroll
    for (int r = 0; r < 4; ++r) {
      const float* rp = redm + (quad * 4 + r) * 4;
      fm[r] = fmaxf(fmaxf(rp[0], rp[1]), fmaxf(rp[2], rp[3]));
    }
    float ex[4][4];
    float ls[4] = {0.f, 0.f, 0.f, 0.f};
#pragma unroll
    for (int j = 0; j < 4; ++j)
#pragma unroll
      for (int r = 0; r < 4; ++r) {
        ex[j][r] = __expf(acc[j][r] - fm[r]);
        ls[r] += ex[j][r];
      }
#pragma unroll
    for (int off = 1; off < 16; off <<= 1)
#pragma unroll
      for (int r = 0; r < 4; ++r) ls[r] += __shfl_xor(ls[r], off);
    if (l15 == 0) {
#pragma unroll
      for (int r = 0; r < 4; ++r) reds[(quad * 4 + r) * 4 + w] = ls[r];
    }
    __syncthreads();
    float inv[4];
#pragma unroll
    for (int r = 0; r < 4; ++r) {
      const float* sp = reds + (quad * 4 + r) * 4;
      inv[r] = 1.0f / (sp[0] + sp[1] + sp[2] + sp[3]);
    }
#pragma unroll
    for (int j = 0; j < 4; ++j) {
      int vg = w * 64 + j * 16 + l15;
#pragma unroll
      for (int r = 0; r < 4; ++r) {
        int n = n0 + quad * 4 + r;
        pbuf[(((size_t)n * NE + e) * 64 + wq) * WW + vg] = f2bf(ex[j][r] * inv[r]);
        raws[j][r] += acc[j][r];
      }
    }
  }

#pragma unroll
  for (int j = 0; j < 4; ++j) {
    int vg = w * 64 + j * 16 + l15;
#pragma unroll
    for (int r = 0; r < 4; ++r) {
      int n = n0 + quad * 4 + r;
      raw[((size_t)n * WW + wc * 64 + wq) * WW + vg] = raws[j][r];
    }
  }
}

// ---------------------------------------------------------------------------
// PV (bf16 MFMA)
__global__ __launch_bounds__(256) void pv_kernel(const unsigned short* __restrict__ pb,
                                                 const unsigned short* __restrict__ vb,
                                                 unsigned short* __restrict__ vob) {
  __shared__ unsigned short As[64 * 72];
  __shared__ unsigned short Bs[64 * 72];
  int t = threadIdx.x, lane = t & 63, w = t >> 6;
  int quad = lane >> 4, l15 = lane & 15;
  int e = blockIdx.x, n = blockIdx.y;
  fx4 acc[4];
#pragma unroll
  for (int j = 0; j < 4; ++j) acc[j] = (fx4){0.f, 0.f, 0.f, 0.f};
  const unsigned short* abase = pb + (((size_t)n * NE + e) * 64) * WW;
  for (int kc = 0; kc < 4; ++kc) {
    for (int c = t; c < 512; c += 256) {
      int row = c >> 3, c8 = c & 7;
      *(int4*)(As + row * 72 + c8 * 8) = *(const int4*)(abase + (size_t)row * WW + kc * 64 + c8 * 8);
    }
    for (int c = t; c < 512; c += 256) {
      int row = c >> 3, c8 = c & 7;
      *(int4*)(Bs + row * 72 + c8 * 8) =
          *(const int4*)(vb + ((size_t)(kc * 64 + row) * NB + n) * 512 + e * 64 + c8 * 8);
    }
    __syncthreads();
#pragma unroll
    for (int kt = 0; kt < 64; kt += 32) {
      bfx8 af = *(const bfx8*)(As + (w * 16 + l15) * 72 + kt + quad * 8);
      bfx8 bfr[4];
#pragma unroll
      for (int j = 0; j < 4; ++j)
        bfr[j] = *(const bfx8*)(Bs + (j * 16 + l15) * 72 + kt + quad * 8);
#pragma unroll
      for (int j = 0; j < 4; ++j)
        acc[j] = __builtin_amdgcn_mfma_f32_16x16x32_bf16(af, bfr[j], acc[j], 0, 0, 0);
    }
    __syncthreads();
  }
#pragma unroll
  for (int j = 0; j < 4; ++j)
#pragma unroll
    for (int r = 0; r < 4; ++r) {
      int wq = w * 16 + quad * 4 + r;
      vob[((size_t)wq * NB + n) * 512 + e * 64 + j * 16 + l15] = f2bf(acc[j][r]);
    }
}

// ---------------------------------------------------------------------------
extern "C" void kernel_launch(void* const* d_in, const int* in_sizes, int n_in,
                              void* d_out, int out_size, void* d_ws, size_t ws_size,
                              hipStream_t stream) {
  const float* fl  = (const float*)d_in[0];
  const float* fr  = (const float*)d_in[1];
  const float* pos = (const float*)d_in[2];
  const int*  pidx = (const int*)d_in[3];
  const float* lnw = (const float*)d_in[4];
  const float* lnb = (const float*)d_in[5];
  const float* ipw = (const float*)d_in[6];
  const float* ipb = (const float*)d_in[7];
  const float* ow  = (const float*)d_in[8];
  const float* ob  = (const float*)d_in[9];

  float* ws   = (float*)d_ws;
  unsigned short* Wpb = (unsigned short*)(ws + OFF_WPB);
  unsigned short* owb = (unsigned short*)(ws + OFF_OWB);
  float* S    = ws + OFF_S;
  float* U    = ws + OFF_U;
  unsigned short* Pq = (unsigned short*)(ws + OFF_PQ);
  unsigned short* Pk = (unsigned short*)(ws + OFF_PK);
  unsigned short* qb = (unsigned short*)(ws + OFF_QB);
  unsigned short* kb = (unsigned short*)(ws + OFF_KB);
  unsigned short* vb = (unsigned short*)(ws + OFF_VB);
  unsigned short* attnb = (unsigned short*)(ws + OFF_ATTN);       // [128][8][64][256] bf16
  unsigned short* vob4  = attnb + (size_t)16777216;               // [4][64][128][512] bf16
  unsigned short* T3  = (unsigned short*)(ws + OFF_T3);
  unsigned short* pb  = (unsigned short*)(ws + OFF_PB);
  unsigned short* posb = (unsigned short*)(ws + OFF_T3);          // 511*512 bf16 overlay
  unsigned short* ipwb = posb + 262144;                           // 1024*512 bf16 overlay

  float* outF = (float*)d_out;                       // [W][N][C]
  float* outR = outF + (size_t)WW * NB * CD;         // raw_attn [N][W][W]

  prep_kernel<<<1536, 256, 0, stream>>>(ipw, ipb, lnw, lnb, Wpb, S, U);
  cvt_kernel<<<128, 256, 0, stream>>>(ow, owb, 32768);
  cvt_kernel<<<128, 256, 0, stream>>>(pos, posb, 32704);          // 511*512/8
  cvt_kernel<<<256, 256, 0, stream>>>(ipw, ipwb, 65536);          // 1024*512/8
  posproj_mfma<<<dim3(4, 8), 256, 0, stream>>>(posb, ipwb, ipb, Pq, Pk);
  gemm_ln<<<dim3(4, 256), 256, 0, stream>>>(fl, Wpb, S, U, qb, qb, 0, SCALING);
  gemm_ln<<<dim3(8, 256), 256, 0, stream>>>(fr, Wpb, S, U, kb, vb, 512, 1.0f);

  for (int wc = 0; wc < NCHUNKS; ++wc) {
    t3_kernel<<<dim3(8, 256), 256, 0, stream>>>(kb, Pq, pidx, T3, wc);
    t1_kernel<<<dim3(8, 128), 256, 0, stream>>>(qb, kb, T3, attnb, wc);
    t2s_kernel<<<dim3(64, 8), 256, 0, stream>>>(qb, Pk, pidx, attnb, pb, outR, wc);
    pv_kernel<<<dim3(8, 128), 256, 0, stream>>>(pb, vb, vob4 + (size_t)wc * 64 * NB * 512);
  }
  gemm_out<<<dim3(4, 256), 256, 0, stream>>>(vob4, owb, ob, fl, outF);
}

// Round 6
// 762.984 us; speedup vs baseline: 1.0528x; 1.0528x over previous
//
#include <hip/hip_runtime.h>

// Problem constants
#define WW 256
#define NB 128      // batch N
#define CD 512      // channels
#define NE 8        // heads
#define HD 64       // head dim
#define NCHUNKS 4
#define SCALING 0.125f

typedef __attribute__((ext_vector_type(8))) short bfx8;
typedef __attribute__((ext_vector_type(4))) float fx4;

// workspace layout (float offsets)
#define OFF_MEAN   0u
#define OFF_RSTD   65536u
#define OFF_WPB    131072u          // 1536*512 bf16
#define OFF_OWB    524288u          // 512*512 bf16
#define OFF_S      655360u
#define OFF_U      656896u
#define OFF_PQ     658432u          // 511*512 bf16 (scaled q_r)
#define OFF_PK     789504u          // 511*512 bf16
#define OFF_QB     920576u          // 256*128*512 bf16
#define OFF_KB     9309184u
#define OFF_VB     17697792u
#define OFF_ATTN   26086400u        // attnb bf16 (33.5MB) + vob4 bf16 (33.5MB); flb/frb overlay pre-loop
#define OFF_T3     42863616u        // 8*256*128*64 bf16 (posb/ipwb overlay pre-loop)
#define OFF_PB     51252224u        // 128*8*64*256 bf16 probs
// total ~61.7M floats = 247 MB

// ---------------------------------------------------------------------------
__device__ __forceinline__ unsigned short f2bf(float f) {
  unsigned u = __builtin_bit_cast(unsigned, f);
  u = (u + 0x7fffu + ((u >> 16) & 1u)) >> 16;
  return (unsigned short)u;
}
__device__ __forceinline__ float bf2f(unsigned short h) {
  unsigned u = ((unsigned)h) << 16;
  return __builtin_bit_cast(float, u);
}
__device__ __forceinline__ int packbf(float lo, float hi) {
  return (int)(((unsigned)f2bf(hi) << 16) | f2bf(lo));
}

#define GLDS16(g, l)                                                          \
  __builtin_amdgcn_global_load_lds(                                           \
      (const __attribute__((address_space(1))) void*)(g),                     \
      (__attribute__((address_space(3))) void*)(l), 16, 0, 0)

// ---------------------------------------------------------------------------
// fp32 -> bf16 convert
__global__ __launch_bounds__(256) void cvt_kernel(const float* __restrict__ a,
                                                  unsigned short* __restrict__ b,
                                                  int n8) {
  int i = blockIdx.x * 256 + threadIdx.x;
  if (i >= n8) return;
  float4 x = ((const float4*)a)[2 * i];
  float4 y = ((const float4*)a)[2 * i + 1];
  int4 o;
  o.x = packbf(x.x, x.y);
  o.y = packbf(x.z, x.w);
  o.z = packbf(y.x, y.y);
  o.w = packbf(y.z, y.w);
  ((int4*)b)[i] = o;
}

// ---------------------------------------------------------------------------
// Row stats for LN folding + fp32->bf16 conversion.
// 1 row per wave; lane owns 8 contiguous elements: 32B contig read, 16B store.
__global__ __launch_bounds__(256) void stats_kernel(const float* __restrict__ L,
                                                    const float* __restrict__ R,
                                                    float* __restrict__ mean,
                                                    float* __restrict__ rstd,
                                                    unsigned short* __restrict__ flb,
                                                    unsigned short* __restrict__ frb) {
  int wave = threadIdx.x >> 6, lane = threadIdx.x & 63;
  int row = blockIdx.x * 4 + wave;
  const float* src = (row < 32768) ? (L + (size_t)row * CD) : (R + (size_t)(row - 32768) * CD);
  unsigned short* drow = (row < 32768) ? (flb + (size_t)row * CD) : (frb + (size_t)(row - 32768) * CD);
  float4 a = *(const float4*)(src + lane * 8);
  float4 b = *(const float4*)(src + lane * 8 + 4);
  int4 o;
  o.x = packbf(a.x, a.y);
  o.y = packbf(a.z, a.w);
  o.z = packbf(b.x, b.y);
  o.w = packbf(b.z, b.w);
  *(int4*)(drow + lane * 8) = o;
  float s  = a.x + a.y + a.z + a.w + b.x + b.y + b.z + b.w;
  float ss = a.x*a.x + a.y*a.y + a.z*a.z + a.w*a.w + b.x*b.x + b.y*b.y + b.z*b.z + b.w*b.w;
#pragma unroll
  for (int off = 32; off > 0; off >>= 1) {
    s  += __shfl_xor(s, off);
    ss += __shfl_xor(ss, off);
  }
  if (lane == 0) {
    float m = s * (1.0f / 512.0f);
    float v = ss * (1.0f / 512.0f) - m * m;
    mean[row] = m;
    rstd[row] = rsqrtf(v + 1e-5f);
  }
}

// ---------------------------------------------------------------------------
// Fold ln_w into in_proj_w (bf16); per-output-row constants S,U.
// Also emits unfolded bf16 ipw rows (first 1024) for posproj.
__global__ __launch_bounds__(256) void prep_kernel(const float* __restrict__ ipw,
                                                   const float* __restrict__ ipb,
                                                   const float* __restrict__ lnw,
                                                   const float* __restrict__ lnb,
                                                   unsigned short* __restrict__ Wpb,
                                                   unsigned short* __restrict__ ipwb,
                                                   float* __restrict__ S,
                                                   float* __restrict__ U) {
  int o = blockIdx.x, t = threadIdx.x;
  float s = 0.f, u = 0.f;
#pragma unroll
  for (int j0 = 0; j0 < 512; j0 += 256) {
    int j = j0 + t;
    float w0 = ipw[(size_t)o * 512 + j];
    float wl = w0 * lnw[j];
    unsigned short h = f2bf(wl);
    Wpb[(size_t)o * 512 + j] = h;
    if (o < 1024) ipwb[(size_t)o * 512 + j] = f2bf(w0);
    s += bf2f(h);
    u += w0 * lnb[j];
  }
  __shared__ float rs[4], ru[4];
  int lane = t & 63, wv = t >> 6;
#pragma unroll
  for (int off = 32; off > 0; off >>= 1) { s += __shfl_xor(s, off); u += __shfl_xor(u, off); }
  if (lane == 0) { rs[wv] = s; ru[wv] = u; }
  __syncthreads();
  if (t == 0) {
    S[o] = rs[0] + rs[1] + rs[2] + rs[3];
    U[o] = ru[0] + ru[1] + ru[2] + ru[3] + ipb[o];
  }
}

// ---------------------------------------------------------------------------
// bf16 MFMA GEMM with LN-fold epilogue, bf16 output. dbuf + vmcnt + swizzle.
// grid: x = m-tiles (fast), y = n-tiles  [R3 configuration]
__global__ __launch_bounds__(256) void gemm_ln(const unsigned short* __restrict__ A,
                                               const unsigned short* __restrict__ Bw,
                                               const float* __restrict__ S,
                                               const float* __restrict__ U,
                                               const float* __restrict__ mean,
                                               const float* __restrict__ rstd,
                                               unsigned short* __restrict__ out0,
                                               unsigned short* __restrict__ out1,
                                               int wOff, int statOff, float scale) {
  __shared__ unsigned short As[2][128 * 32];
  __shared__ unsigned short Bs[2][128 * 32];
  int t = threadIdx.x;
  int lane = t & 63, w = t >> 6;
  int quad = lane >> 4, l15 = lane & 15;
  int wm = w >> 1, wn = w & 1;
  int m0 = blockIdx.x * 128, n0 = blockIdx.y * 128;

  int cs = ((lane & 3) ^ ((lane >> 3) & 3)) * 8;
  unsigned lo0 = (unsigned)(w * 16) * 32;
  unsigned lo1 = (unsigned)(64 + w * 16) * 32;
  const unsigned short* gA0 = A + (size_t)(m0 + w * 16 + (lane >> 2)) * 512 + cs;
  const unsigned short* gA1 = gA0 + (size_t)64 * 512;
  const unsigned short* gB0 = Bw + (size_t)(wOff + n0 + w * 16 + (lane >> 2)) * 512 + cs;
  const unsigned short* gB1 = gB0 + (size_t)64 * 512;

  fx4 acc[4][4];
#pragma unroll
  for (int i = 0; i < 4; ++i)
#pragma unroll
    for (int j = 0; j < 4; ++j) acc[i][j] = (fx4){0.f, 0.f, 0.f, 0.f};

  int ro = (quad ^ ((l15 >> 1) & 3)) * 8;

#define STAGE_G(buf, kk)                                                      \
  do {                                                                        \
    GLDS16(gA0 + (kk), &As[buf][lo0]);                                        \
    GLDS16(gA1 + (kk), &As[buf][lo1]);                                        \
    GLDS16(gB0 + (kk), &Bs[buf][lo0]);                                        \
    GLDS16(gB1 + (kk), &Bs[buf][lo1]);                                        \
  } while (0)

#define COMPUTE_G(buf)                                                        \
  do {                                                                        \
    const unsigned short* Ab = &As[buf][0];                                   \
    const unsigned short* Bb = &Bs[buf][0];                                   \
    bfx8 af[4], bfr[4];                                                       \
    _Pragma("unroll")                                                         \
    for (int i = 0; i < 4; ++i)                                               \
      af[i] = *(const bfx8*)(Ab + (size_t)(wm * 64 + i * 16 + l15) * 32 + ro);\
    _Pragma("unroll")                                                         \
    for (int j = 0; j < 4; ++j)                                               \
      bfr[j] = *(const bfx8*)(Bb + (size_t)(wn * 64 + j * 16 + l15) * 32 + ro);\
    _Pragma("unroll")                                                         \
    for (int i = 0; i < 4; ++i)                                               \
      _Pragma("unroll")                                                       \
      for (int j = 0; j < 4; ++j)                                             \
        acc[i][j] = __builtin_amdgcn_mfma_f32_16x16x32_bf16(af[i], bfr[j], acc[i][j], 0, 0, 0); \
  } while (0)

  STAGE_G(0, 0);
  int cur = 0;
  for (int kt = 0; kt < 480; kt += 32) {
    STAGE_G(cur ^ 1, kt + 32);
    asm volatile("s_waitcnt vmcnt(4)" ::: "memory");
    __builtin_amdgcn_s_barrier();
    __builtin_amdgcn_sched_barrier(0);
    COMPUTE_G(cur);
    asm volatile("s_waitcnt lgkmcnt(0)" ::: "memory");
    __builtin_amdgcn_s_barrier();
    __builtin_amdgcn_sched_barrier(0);
    cur ^= 1;
  }
  asm volatile("s_waitcnt vmcnt(0)" ::: "memory");
  __builtin_amdgcn_s_barrier();
  __builtin_amdgcn_sched_barrier(0);
  COMPUTE_G(cur);

  float mn[16], rs[16];
#pragma unroll
  for (int i = 0; i < 4; ++i)
#pragma unroll
    for (int r = 0; r < 4; ++r) {
      int m = statOff + m0 + wm * 64 + i * 16 + quad * 4 + r;
      mn[i * 4 + r] = mean[m];
      rs[i * 4 + r] = rstd[m];
    }
#pragma unroll
  for (int j = 0; j < 4; ++j) {
    int oc = n0 + wn * 64 + j * 16 + l15;
    int o = wOff + oc;
    float Sv = S[o], Uv = U[o];
    unsigned short* dst; int cc;
    if (oc < 512) { dst = out0; cc = oc; } else { dst = out1; cc = oc - 512; }
#pragma unroll
    for (int i = 0; i < 4; ++i)
#pragma unroll
      for (int r = 0; r < 4; ++r) {
        int m = m0 + wm * 64 + i * 16 + quad * 4 + r;
        dst[(size_t)m * 512 + cc] =
            f2bf(((acc[i][j][r] - mn[i * 4 + r] * Sv) * rs[i * 4 + r] + Uv) * scale);
      }
  }
#undef STAGE_G
#undef COMPUTE_G
}

// ---------------------------------------------------------------------------
// bf16 MFMA GEMM out-proj over ALL chunks: out[g,o] = fl[g,o] + vob4@owb + ob
__global__ __launch_bounds__(256) void gemm_out(const unsigned short* __restrict__ A,
                                                const unsigned short* __restrict__ Bw,
                                                const float* __restrict__ ob,
                                                const float* __restrict__ fl,
                                                float* __restrict__ out) {
  __shared__ unsigned short As[2][128 * 32];
  __shared__ unsigned short Bs[2][128 * 32];
  int t = threadIdx.x;
  int lane = t & 63, w = t >> 6;
  int quad = lane >> 4, l15 = lane & 15;
  int wm = w >> 1, wn = w & 1;
  int n0 = blockIdx.x * 128, m0 = blockIdx.y * 128;

  int cs = ((lane & 3) ^ ((lane >> 3) & 3)) * 8;
  unsigned lo0 = (unsigned)(w * 16) * 32;
  unsigned lo1 = (unsigned)(64 + w * 16) * 32;
  const unsigned short* gA0 = A + (size_t)(m0 + w * 16 + (lane >> 2)) * 512 + cs;
  const unsigned short* gA1 = gA0 + (size_t)64 * 512;
  const unsigned short* gB0 = Bw + (size_t)(n0 + w * 16 + (lane >> 2)) * 512 + cs;
  const unsigned short* gB1 = gB0 + (size_t)64 * 512;

  fx4 acc[4][4];
#pragma unroll
  for (int i = 0; i < 4; ++i)
#pragma unroll
    for (int j = 0; j < 4; ++j) acc[i][j] = (fx4){0.f, 0.f, 0.f, 0.f};

  int ro = (quad ^ ((l15 >> 1) & 3)) * 8;

#define STAGE_O(buf, kk)                                                      \
  do {                                                                        \
    GLDS16(gA0 + (kk), &As[buf][lo0]);                                        \
    GLDS16(gA1 + (kk), &As[buf][lo1]);                                        \
    GLDS16(gB0 + (kk), &Bs[buf][lo0]);                                        \
    GLDS16(gB1 + (kk), &Bs[buf][lo1]);                                        \
  } while (0)

#define COMPUTE_O(buf)                                                        \
  do {                                                                        \
    const unsigned short* Ab = &As[buf][0];                                   \
    const unsigned short* Bb = &Bs[buf][0];                                   \
    bfx8 af[4], bfr[4];                                                       \
    _Pragma("unroll")                                                         \
    for (int i = 0; i < 4; ++i)                                               \
      af[i] = *(const bfx8*)(Ab + (size_t)(wm * 64 + i * 16 + l15) * 32 + ro);\
    _Pragma("unroll")                                                         \
    for (int j = 0; j < 4; ++j)                                               \
      bfr[j] = *(const bfx8*)(Bb + (size_t)(wn * 64 + j * 16 + l15) * 32 + ro);\
    _Pragma("unroll")                                                         \
    for (int i = 0; i < 4; ++i)                                               \
      _Pragma("unroll")                                                       \
      for (int j = 0; j < 4; ++j)                                             \
        acc[i][j] = __builtin_amdgcn_mfma_f32_16x16x32_bf16(af[i], bfr[j], acc[i][j], 0, 0, 0); \
  } while (0)

  STAGE_O(0, 0);
  int cur = 0;
  for (int kt = 0; kt < 480; kt += 32) {
    STAGE_O(cur ^ 1, kt + 32);
    asm volatile("s_waitcnt vmcnt(4)" ::: "memory");
    __builtin_amdgcn_s_barrier();
    __builtin_amdgcn_sched_barrier(0);
    COMPUTE_O(cur);
    asm volatile("s_waitcnt lgkmcnt(0)" ::: "memory");
    __builtin_amdgcn_s_barrier();
    __builtin_amdgcn_sched_barrier(0);
    cur ^= 1;
  }
  asm volatile("s_waitcnt vmcnt(0)" ::: "memory");
  __builtin_amdgcn_s_barrier();
  __builtin_amdgcn_sched_barrier(0);
  COMPUTE_O(cur);

#pragma unroll
  for (int j = 0; j < 4; ++j) {
    int o = n0 + wn * 64 + j * 16 + l15;
    float bias = ob[o];
#pragma unroll
    for (int i = 0; i < 4; ++i)
#pragma unroll
      for (int r = 0; r < 4; ++r) {
        int m = m0 + wm * 64 + i * 16 + quad * 4 + r;
        size_t go = (size_t)m * 512 + o;
        out[go] = acc[i][j][r] + bias + fl[go];
      }
  }
#undef STAGE_O
#undef COMPUTE_O
}

// ---------------------------------------------------------------------------
// pos table projection via MFMA (bf16 inputs converted by cvt/prep).
__global__ __launch_bounds__(256) void posproj_mfma(const unsigned short* __restrict__ Apos,
                                                    const unsigned short* __restrict__ Bw,
                                                    const float* __restrict__ ipb,
                                                    unsigned short* __restrict__ Pq,
                                                    unsigned short* __restrict__ Pk) {
  __shared__ unsigned short As[2][128 * 32];
  __shared__ unsigned short Bs[2][128 * 32];
  int t = threadIdx.x;
  int lane = t & 63, w = t >> 6;
  int quad = lane >> 4, l15 = lane & 15;
  int wm = w >> 1, wn = w & 1;
  int m0 = blockIdx.x * 128, n0 = blockIdx.y * 128;

  int cs = ((lane & 3) ^ ((lane >> 3) & 3)) * 8;
  unsigned lo0 = (unsigned)(w * 16) * 32;
  unsigned lo1 = (unsigned)(64 + w * 16) * 32;
  int ar0 = m0 + w * 16 + (lane >> 2); if (ar0 > 510) ar0 = 510;
  int ar1 = m0 + 64 + w * 16 + (lane >> 2); if (ar1 > 510) ar1 = 510;
  const unsigned short* gA0 = Apos + (size_t)ar0 * 512 + cs;
  const unsigned short* gA1 = Apos + (size_t)ar1 * 512 + cs;
  const unsigned short* gB0 = Bw + (size_t)(n0 + w * 16 + (lane >> 2)) * 512 + cs;
  const unsigned short* gB1 = gB0 + (size_t)64 * 512;

  fx4 acc[4][4];
#pragma unroll
  for (int i = 0; i < 4; ++i)
#pragma unroll
    for (int j = 0; j < 4; ++j) acc[i][j] = (fx4){0.f, 0.f, 0.f, 0.f};

  int ro = (quad ^ ((l15 >> 1) & 3)) * 8;

#define STAGE_P(buf, kk)                                                      \
  do {                                                                        \
    GLDS16(gA0 + (kk), &As[buf][lo0]);                                        \
    GLDS16(gA1 + (kk), &As[buf][lo1]);                                        \
    GLDS16(gB0 + (kk), &Bs[buf][lo0]);                                        \
    GLDS16(gB1 + (kk), &Bs[buf][lo1]);                                        \
  } while (0)

#define COMPUTE_P(buf)                                                        \
  do {                                                                        \
    const unsigned short* Ab = &As[buf][0];                                   \
    const unsigned short* Bb = &Bs[buf][0];                                   \
    bfx8 af[4], bfr[4];                                                       \
    _Pragma("unroll")                                                         \
    for (int i = 0; i < 4; ++i)                                               \
      af[i] = *(const bfx8*)(Ab + (size_t)(wm * 64 + i * 16 + l15) * 32 + ro);\
    _Pragma("unroll")                                                         \
    for (int j = 0; j < 4; ++j)                                               \
      bfr[j] = *(const bfx8*)(Bb + (size_t)(wn * 64 + j * 16 + l15) * 32 + ro);\
    _Pragma("unroll")                                                         \
    for (int i = 0; i < 4; ++i)                                               \
      _Pragma("unroll")                                                       \
      for (int j = 0; j < 4; ++j)                                             \
        acc[i][j] = __builtin_amdgcn_mfma_f32_16x16x32_bf16(af[i], bfr[j], acc[i][j], 0, 0, 0); \
  } while (0)

  STAGE_P(0, 0);
  int cur = 0;
  for (int kt = 0; kt < 480; kt += 32) {
    STAGE_P(cur ^ 1, kt + 32);
    asm volatile("s_waitcnt vmcnt(4)" ::: "memory");
    __builtin_amdgcn_s_barrier();
    __builtin_amdgcn_sched_barrier(0);
    COMPUTE_P(cur);
    asm volatile("s_waitcnt lgkmcnt(0)" ::: "memory");
    __builtin_amdgcn_s_barrier();
    __builtin_amdgcn_sched_barrier(0);
    cur ^= 1;
  }
  asm volatile("s_waitcnt vmcnt(0)" ::: "memory");
  __builtin_amdgcn_s_barrier();
  __builtin_amdgcn_sched_barrier(0);
  COMPUTE_P(cur);

#pragma unroll
  for (int j = 0; j < 4; ++j) {
    int o = n0 + wn * 64 + j * 16 + l15;
    float bias = ipb[o];
    float scale = (o < 512) ? SCALING : 1.0f;
    unsigned short* dst; int cc;
    if (o < 512) { dst = Pq; cc = o; } else { dst = Pk; cc = o - 512; }
#pragma unroll
    for (int i = 0; i < 4; ++i)
#pragma unroll
      for (int r = 0; r < 4; ++r) {
        int m = m0 + wm * 64 + i * 16 + quad * 4 + r;
        if (m < 511)
          dst[(size_t)m * 512 + cc] = f2bf((acc[i][j][r] + bias) * scale);
      }
  }
#undef STAGE_P
#undef COMPUTE_P
}

// ---------------------------------------------------------------------------
// term3 (bf16 MFMA): T3[e][v][n][wq] = sum_h k[v,n,e,h] * q_r[wq,v,e,h]
__global__ __launch_bounds__(256) void t3_kernel(const unsigned short* __restrict__ kb,
                                                 const unsigned short* __restrict__ Pq,
                                                 const int* __restrict__ idx,
                                                 unsigned short* __restrict__ T3, int wc) {
  __shared__ unsigned short As[128 * 72];
  __shared__ unsigned short Bs[64 * 72];
  int t = threadIdx.x, lane = t & 63, w = t >> 6;
  int quad = lane >> 4, l15 = lane & 15;
  int e = blockIdx.x, v = blockIdx.y;
  const unsigned short* asrc = kb + ((size_t)v * NB) * 512 + e * 64;
  for (int c = t; c < 1024; c += 256) {
    int row = c >> 3, c8 = c & 7;
    *(int4*)(As + row * 72 + c8 * 8) = *(const int4*)(asrc + (size_t)row * 512 + c8 * 8);
  }
  for (int c = t; c < 512; c += 256) {
    int row = c >> 3, c8 = c & 7;
    int ri = idx[(wc * 64 + row) * WW + v];
    *(int4*)(Bs + row * 72 + c8 * 8) = *(const int4*)(Pq + (size_t)ri * 512 + e * 64 + c8 * 8);
  }
  __syncthreads();
  fx4 acc[2][4];
#pragma unroll
  for (int i = 0; i < 2; ++i)
#pragma unroll
    for (int j = 0; j < 4; ++j) acc[i][j] = (fx4){0.f, 0.f, 0.f, 0.f};
#pragma unroll
  for (int kt = 0; kt < 64; kt += 32) {
    bfx8 af[2], bfr[4];
#pragma unroll
    for (int i = 0; i < 2; ++i)
      af[i] = *(const bfx8*)(As + (w * 32 + i * 16 + l15) * 72 + kt + quad * 8);
#pragma unroll
    for (int j = 0; j < 4; ++j)
      bfr[j] = *(const bfx8*)(Bs + (j * 16 + l15) * 72 + kt + quad * 8);
#pragma unroll
    for (int i = 0; i < 2; ++i)
#pragma unroll
      for (int j = 0; j < 4; ++j)
        acc[i][j] = __builtin_amdgcn_mfma_f32_16x16x32_bf16(af[i], bfr[j], acc[i][j], 0, 0, 0);
  }
#pragma unroll
  for (int i = 0; i < 2; ++i)
#pragma unroll
    for (int j = 0; j < 4; ++j)
#pragma unroll
      for (int r = 0; r < 4; ++r) {
        int n = w * 32 + i * 16 + quad * 4 + r;
        int wq = j * 16 + l15;
        T3[(((size_t)e * WW + v) * NB + n) * 64 + wq] = f2bf(acc[i][j][r]);
      }
}

// ---------------------------------------------------------------------------
// term1 + term3-merge (bf16 MFMA), write-only first writer of attnb (bf16)
__global__ __launch_bounds__(256) void t1_kernel(const unsigned short* __restrict__ qb,
                                                 const unsigned short* __restrict__ kb,
                                                 const unsigned short* __restrict__ T3,
                                                 unsigned short* __restrict__ attnb, int wc) {
  __shared__ unsigned short As[64 * 72];
  __shared__ unsigned short Bs[256 * 72];
  int t = threadIdx.x, lane = t & 63, w = t >> 6;
  int quad = lane >> 4, l15 = lane & 15;
  int e = blockIdx.x, n = blockIdx.y;
  const unsigned short* asrc = qb + ((size_t)(wc * 64) * NB + n) * 512 + e * 64;
  for (int c = t; c < 512; c += 256) {
    int row = c >> 3, c8 = c & 7;
    *(int4*)(As + row * 72 + c8 * 8) = *(const int4*)(asrc + (size_t)row * NB * 512 + c8 * 8);
  }
  const unsigned short* bsrc = kb + (size_t)n * 512 + e * 64;
  for (int c = t; c < 2048; c += 256) {
    int row = c >> 3, c8 = c & 7;
    *(int4*)(Bs + row * 72 + c8 * 8) = *(const int4*)(bsrc + (size_t)row * NB * 512 + c8 * 8);
  }
  __syncthreads();
  fx4 acc[4][4];
#pragma unroll
  for (int i = 0; i < 4; ++i)
#pragma unroll
    for (int j = 0; j < 4; ++j) acc[i][j] = (fx4){0.f, 0.f, 0.f, 0.f};
#pragma unroll
  for (int kt = 0; kt < 64; kt += 32) {
    bfx8 af[4], bfr[4];
#pragma unroll
    for (int i = 0; i < 4; ++i)
      af[i] = *(const bfx8*)(As + (i * 16 + l15) * 72 + kt + quad * 8);
#pragma unroll
    for (int j = 0; j < 4; ++j)
      bfr[j] = *(const bfx8*)(Bs + (w * 64 + j * 16 + l15) * 72 + kt + quad * 8);
#pragma unroll
    for (int i = 0; i < 4; ++i)
#pragma unroll
      for (int j = 0; j < 4; ++j)
        acc[i][j] = __builtin_amdgcn_mfma_f32_16x16x32_bf16(af[i], bfr[j], acc[i][j], 0, 0, 0);
  }
  __syncthreads();
  const unsigned short* tsrc = T3 + ((size_t)e * WW * NB + n) * 64;
  for (int c = t; c < 2048; c += 256) {
    int row = c >> 3, c8 = c & 7;
    *(int4*)(Bs + row * 72 + c8 * 8) = *(const int4*)(tsrc + (size_t)row * NB * 64 + c8 * 8);
  }
  __syncthreads();
#pragma unroll
  for (int i = 0; i < 4; ++i)
#pragma unroll
    for (int j = 0; j < 4; ++j) {
      int vg = w * 64 + j * 16 + l15;
      ushort4 t3v = *(const ushort4*)(Bs + (size_t)vg * 72 + i * 16 + quad * 4);
      const unsigned short tv[4] = {t3v.x, t3v.y, t3v.z, t3v.w};
#pragma unroll
      for (int r = 0; r < 4; ++r) {
        int wq = i * 16 + quad * 4 + r;
        attnb[(((size_t)n * NE + e) * 64 + wq) * WW + vg] = f2bf(acc[i][j][r] + bf2f(tv[r]));
      }
    }
}

// ---------------------------------------------------------------------------
// term2 + softmax fused; attn read is bf16
__global__ __launch_bounds__(256) void t2s_kernel(const unsigned short* __restrict__ qb,
                                                  const unsigned short* __restrict__ Pk,
                                                  const int* __restrict__ idx,
                                                  const unsigned short* __restrict__ attnb,
                                                  unsigned short* __restrict__ pbuf,
                                                  float* __restrict__ raw, int wc) {
  __shared__ unsigned short As[16 * 72];
  __shared__ unsigned short Bs[256 * 72];
  __shared__ int idxs[256];
  __shared__ float redm[16 * 4];
  __shared__ float reds[16 * 4];
  int t = threadIdx.x, lane = t & 63, w = t >> 6;
  int quad = lane >> 4, l15 = lane & 15;
  int wq = blockIdx.x, nt = blockIdx.y;
  int n0 = nt * 16;
  idxs[t] = idx[((size_t)(wc * 64 + wq)) * WW + t];

  fx4 raws[4];
#pragma unroll
  for (int j = 0; j < 4; ++j) raws[j] = (fx4){0.f, 0.f, 0.f, 0.f};

  const unsigned short* abase = qb + ((size_t)(wc * 64 + wq) * NB + n0) * 512;

  for (int e = 0; e < NE; ++e) {
    __syncthreads();
    if (t < 128) {
      int row = t >> 3, c8 = t & 7;
      *(int4*)(As + row * 72 + c8 * 8) = *(const int4*)(abase + (size_t)row * 512 + e * 64 + c8 * 8);
    }
    for (int c = t; c < 2048; c += 256) {
      int row = c >> 3, c8 = c & 7;
      int ri = idxs[row];
      *(int4*)(Bs + row * 72 + c8 * 8) = *(const int4*)(Pk + (size_t)ri * 512 + e * 64 + c8 * 8);
    }
    __syncthreads();

    fx4 acc[4];
#pragma unroll
    for (int j = 0; j < 4; ++j) acc[j] = (fx4){0.f, 0.f, 0.f, 0.f};
    bfx8 af0 = *(const bfx8*)(As + l15 * 72 + quad * 8);
    bfx8 af1 = *(const bfx8*)(As + l15 * 72 + 32 + quad * 8);
#pragma unroll
    for (int j = 0; j < 4; ++j) {
      bfx8 b0 = *(const bfx8*)(Bs + (w * 64 + j * 16 + l15) * 72 + quad * 8);
      acc[j] = __builtin_amdgcn_mfma_f32_16x16x32_bf16(af0, b0, acc[j], 0, 0, 0);
    }
#pragma unroll
    for (int j = 0; j < 4; ++j) {
      bfx8 b1 = *(const bfx8*)(Bs + (w * 64 + j * 16 + l15) * 72 + 32 + quad * 8);
      acc[j] = __builtin_amdgcn_mfma_f32_16x16x32_bf16(af1, b1, acc[j], 0, 0, 0);
    }

#pragma unroll
    for (int j = 0; j < 4; ++j) {
      int vg = w * 64 + j * 16 + l15;
#pragma unroll
      for (int r = 0; r < 4; ++r) {
        int n = n0 + quad * 4 + r;
        acc[j][r] += bf2f(attnb[(((size_t)n * NE + e) * 64 + wq) * WW + vg]);
      }
    }

    float rm[4];
#pragma unroll
    for (int r = 0; r < 4; ++r)
      rm[r] = fmaxf(fmaxf(acc[0][r], acc[1][r]), fmaxf(acc[2][r], acc[3][r]));
#pragma unroll
    for (int off = 1; off < 16; off <<= 1)
#pragma unroll
      for (int r = 0; r < 4; ++r) rm[r] = fmaxf(rm[r], __shfl_xor(rm[r], off));
    if (l15 == 0) {
#pragma unroll
      for (int r = 0; r < 4; ++r) redm[(quad * 4 + r) * 4 + w] = rm[r];
    }
    __syncthreads();
    float fm[4];
#pragma unroll
    for (int r = 0; r < 4; ++r) {
      const float* rp = redm + (quad * 4 + r) * 4;
      fm[r] = fmaxf(fmaxf(rp[0], rp[1]), fmaxf(rp[2], rp[3]));
    }
    float ex[4][4];
    float ls[4] = {0.f, 0.f, 0.f, 0.f};
#pragma unroll
    for (int j = 0; j < 4; ++j)
#pragma unroll
      for (int r = 0; r < 4; ++r) {
        ex[j][r] = __expf(acc[j][r] - fm[r]);
        ls[r] += ex[j][r];
      }
#pragma unroll
    for (int off = 1; off < 16; off <<= 1)
#pragma unroll
      for (int r = 0; r < 4; ++r) ls[r] += __shfl_xor(ls[r], off);
    if (l15 == 0) {
#pragma unroll
      for (int r = 0; r < 4; ++r) reds[(quad * 4 + r) * 4 + w] = ls[r];
    }
    __syncthreads();
    float inv[4];
#pragma unroll
    for (int r = 0; r < 4; ++r) {
      const float* sp = reds + (quad * 4 + r) * 4;
      inv[r] = 1.0f / (sp[0] + sp[1] + sp[2] + sp[3]);
    }
#pragma unroll
    for (int j = 0; j < 4; ++j) {
      int vg = w * 64 + j * 16 + l15;
#pragma unroll
      for (int r = 0; r < 4; ++r) {
        int n = n0 + quad * 4 + r;
        pbuf[(((size_t)n * NE + e) * 64 + wq) * WW + vg] = f2bf(ex[j][r] * inv[r]);
        raws[j][r] += acc[j][r];
      }
    }
  }

#pragma unroll
  for (int j = 0; j < 4; ++j) {
    int vg = w * 64 + j * 16 + l15;
#pragma unroll
    for (int r = 0; r < 4; ++r) {
      int n = n0 + quad * 4 + r;
      raw[((size_t)n * WW + wc * 64 + wq) * WW + vg] = raws[j][r];
    }
  }
}

// ---------------------------------------------------------------------------
// PV (bf16 MFMA)
__global__ __launch_bounds__(256) void pv_kernel(const unsigned short* __restrict__ pb,
                                                 const unsigned short* __restrict__ vb,
                                                 unsigned short* __restrict__ vob) {
  __shared__ unsigned short As[64 * 72];
  __shared__ unsigned short Bs[64 * 72];
  int t = threadIdx.x, lane = t & 63, w = t >> 6;
  int quad = lane >> 4, l15 = lane & 15;
  int e = blockIdx.x, n = blockIdx.y;
  fx4 acc[4];
#pragma unroll
  for (int j = 0; j < 4; ++j) acc[j] = (fx4){0.f, 0.f, 0.f, 0.f};
  const unsigned short* abase = pb + (((size_t)n * NE + e) * 64) * WW;
  for (int kc = 0; kc < 4; ++kc) {
    for (int c = t; c < 512; c += 256) {
      int row = c >> 3, c8 = c & 7;
      *(int4*)(As + row * 72 + c8 * 8) = *(const int4*)(abase + (size_t)row * WW + kc * 64 + c8 * 8);
    }
    for (int c = t; c < 512; c += 256) {
      int row = c >> 3, c8 = c & 7;
      *(int4*)(Bs + row * 72 + c8 * 8) =
          *(const int4*)(vb + ((size_t)(kc * 64 + row) * NB + n) * 512 + e * 64 + c8 * 8);
    }
    __syncthreads();
#pragma unroll
    for (int kt = 0; kt < 64; kt += 32) {
      bfx8 af = *(const bfx8*)(As + (w * 16 + l15) * 72 + kt + quad * 8);
      bfx8 bfr[4];
#pragma unroll
      for (int j = 0; j < 4; ++j)
        bfr[j] = *(const bfx8*)(Bs + (j * 16 + l15) * 72 + kt + quad * 8);
#pragma unroll
      for (int j = 0; j < 4; ++j)
        acc[j] = __builtin_amdgcn_mfma_f32_16x16x32_bf16(af, bfr[j], acc[j], 0, 0, 0);
    }
    __syncthreads();
  }
#pragma unroll
  for (int j = 0; j < 4; ++j)
#pragma unroll
    for (int r = 0; r < 4; ++r) {
      int wq = w * 16 + quad * 4 + r;
      vob[((size_t)wq * NB + n) * 512 + e * 64 + j * 16 + l15] = f2bf(acc[j][r]);
    }
}

// ---------------------------------------------------------------------------
extern "C" void kernel_launch(void* const* d_in, const int* in_sizes, int n_in,
                              void* d_out, int out_size, void* d_ws, size_t ws_size,
                              hipStream_t stream) {
  const float* fl  = (const float*)d_in[0];
  const float* fr  = (const float*)d_in[1];
  const float* pos = (const float*)d_in[2];
  const int*  pidx = (const int*)d_in[3];
  const float* lnw = (const float*)d_in[4];
  const float* lnb = (const float*)d_in[5];
  const float* ipw = (const float*)d_in[6];
  const float* ipb = (const float*)d_in[7];
  const float* ow  = (const float*)d_in[8];
  const float* ob  = (const float*)d_in[9];

  float* ws   = (float*)d_ws;
  float* mean = ws + OFF_MEAN;
  float* rstd = ws + OFF_RSTD;
  unsigned short* Wpb = (unsigned short*)(ws + OFF_WPB);
  unsigned short* owb = (unsigned short*)(ws + OFF_OWB);
  float* S    = ws + OFF_S;
  float* U    = ws + OFF_U;
  unsigned short* Pq = (unsigned short*)(ws + OFF_PQ);
  unsigned short* Pk = (unsigned short*)(ws + OFF_PK);
  unsigned short* qb = (unsigned short*)(ws + OFF_QB);
  unsigned short* kb = (unsigned short*)(ws + OFF_KB);
  unsigned short* vb = (unsigned short*)(ws + OFF_VB);
  unsigned short* attnb = (unsigned short*)(ws + OFF_ATTN);       // [128][8][64][256] bf16
  unsigned short* vob4  = attnb + (size_t)16777216;               // [4][64][128][512] bf16
  unsigned short* T3  = (unsigned short*)(ws + OFF_T3);
  unsigned short* pb  = (unsigned short*)(ws + OFF_PB);
  // bf16 staging overlays (consumed before their regions' first real writes)
  unsigned short* flb = (unsigned short*)(ws + OFF_ATTN);
  unsigned short* frb = flb + (size_t)32768 * 512;
  unsigned short* posb = (unsigned short*)(ws + OFF_T3);          // 511*512 bf16 overlay
  unsigned short* ipwb = posb + 262144;                           // 1024*512 bf16 overlay

  float* outF = (float*)d_out;                       // [W][N][C]
  float* outR = outF + (size_t)WW * NB * CD;         // raw_attn [N][W][W]

  stats_kernel<<<16384, 256, 0, stream>>>(fl, fr, mean, rstd, flb, frb);
  prep_kernel<<<1536, 256, 0, stream>>>(ipw, ipb, lnw, lnb, Wpb, ipwb, S, U);
  cvt_kernel<<<128, 256, 0, stream>>>(ow, owb, 32768);
  cvt_kernel<<<128, 256, 0, stream>>>(pos, posb, 32704);          // 511*512/8
  posproj_mfma<<<dim3(4, 8), 256, 0, stream>>>(posb, ipwb, ipb, Pq, Pk);
  gemm_ln<<<dim3(256, 4), 256, 0, stream>>>(flb, Wpb, S, U, mean, rstd, qb, qb, 0, 0, SCALING);
  gemm_ln<<<dim3(256, 8), 256, 0, stream>>>(frb, Wpb, S, U, mean, rstd, kb, vb, 512, 32768, 1.0f);

  for (int wc = 0; wc < NCHUNKS; ++wc) {
    t3_kernel<<<dim3(8, 256), 256, 0, stream>>>(kb, Pq, pidx, T3, wc);
    t1_kernel<<<dim3(8, 128), 256, 0, stream>>>(qb, kb, T3, attnb, wc);
    t2s_kernel<<<dim3(64, 8), 256, 0, stream>>>(qb, Pk, pidx, attnb, pb, outR, wc);
    pv_kernel<<<dim3(8, 128), 256, 0, stream>>>(pb, vb, vob4 + (size_t)wc * 64 * NB * 512);
  }
  gemm_out<<<dim3(4, 256), 256, 0, stream>>>(vob4, owb, ob, fl, outF);
}